// Round 1
// baseline (429.448 us; speedup 1.0000x reference)
//
#include <hip/hip_runtime.h>

// LoRALinear: out[8192,4096] = x[8192,4096] @ W.T + 2.0 * (x @ A.T) @ B.T
// Strategy: W_eff = W + 2*B@A (bf16), x -> bf16, one MFMA GEMM out = x @ W_eff.T

#define N_ROWS 8192
#define K_DIM  4096
#define N_COLS 4096
#define RANK   16

typedef __bf16 bf16x8 __attribute__((ext_vector_type(8)));
typedef float  f32x4  __attribute__((ext_vector_type(4)));

__device__ __forceinline__ unsigned short f2bf(float f) {
  unsigned int u = __builtin_bit_cast(unsigned int, f);
  u += 0x7FFFu + ((u >> 16) & 1u);   // round-to-nearest-even
  return (unsigned short)(u >> 16);
}

// ---------------- conversion kernels ----------------

__global__ __launch_bounds__(256) void conv_x_kernel(const float* __restrict__ x,
                                                     unsigned short* __restrict__ xb) {
  size_t idx = (size_t)blockIdx.x * blockDim.x + threadIdx.x;
  const float4 v = *reinterpret_cast<const float4*>(x + idx * 4);
  ushort4 r;
  r.x = f2bf(v.x); r.y = f2bf(v.y); r.z = f2bf(v.z); r.w = f2bf(v.w);
  *reinterpret_cast<ushort4*>(xb + idx * 4) = r;
}

__global__ __launch_bounds__(256) void make_weff_kernel(const float* __restrict__ w,
                                                        const float* __restrict__ A,
                                                        const float* __restrict__ Bm,
                                                        unsigned short* __restrict__ wb) {
  size_t idx = (size_t)blockIdx.x * blockDim.x + threadIdx.x;   // [0, 4096*1024)
  int o  = (int)(idx >> 10);
  int ic = (int)(idx & 1023) << 2;
  const float4 wv = *reinterpret_cast<const float4*>(w + (size_t)o * K_DIM + ic);
  float a0 = wv.x, a1 = wv.y, a2 = wv.z, a3 = wv.w;
  float br[RANK];
#pragma unroll
  for (int r4 = 0; r4 < RANK / 4; ++r4) {
    const float4 bv = *reinterpret_cast<const float4*>(Bm + (size_t)o * RANK + r4 * 4);
    br[r4 * 4 + 0] = bv.x; br[r4 * 4 + 1] = bv.y;
    br[r4 * 4 + 2] = bv.z; br[r4 * 4 + 3] = bv.w;
  }
#pragma unroll
  for (int r = 0; r < RANK; ++r) {
    const float4 av = *reinterpret_cast<const float4*>(A + (size_t)r * K_DIM + ic);
    float b2 = br[r] * 2.0f;  // SCALING folded here
    a0 += b2 * av.x; a1 += b2 * av.y; a2 += b2 * av.z; a3 += b2 * av.w;
  }
  ushort4 rr;
  rr.x = f2bf(a0); rr.y = f2bf(a1); rr.z = f2bf(a2); rr.w = f2bf(a3);
  *reinterpret_cast<ushort4*>(wb + (size_t)o * K_DIM + ic) = rr;
}

// ---------------- bf16 MFMA GEMM (m97 structure: 128x128 tile, BK=32) ----------------

#define BM 128
#define BN 128
#define BK 32

__device__ __forceinline__ void gload_lds16(const void* g, void* l) {
  __builtin_amdgcn_global_load_lds(
      (__attribute__((address_space(1))) void*)g,
      (__attribute__((address_space(3))) void*)l, 16, 0, 0);
}

__global__ __launch_bounds__(256, 2) void gemm_bf16_kernel(
    const unsigned short* __restrict__ xb, const unsigned short* __restrict__ wb,
    float* __restrict__ out) {
  __shared__ __align__(16) unsigned short As[BM * BK];   // [128][32] row-major, 8 KiB
  __shared__ __align__(16) unsigned short Bs[BN * BK];

  const int t  = threadIdx.x;
  const int wv = t >> 6;      // wave 0..3
  const int l  = t & 63;
  const int lr = l & 15;
  const int lk = l >> 4;

  // XCD-aware bijective swizzle (2048 blocks % 8 XCDs == 0)
  const int nwg  = gridDim.x;
  const int cpx  = nwg >> 3;
  const int bid  = blockIdx.x;
  const int sbid = (bid & 7) * cpx + (bid >> 3);
  const int nbn  = N_COLS / BN;         // 32
  const int bm   = sbid / nbn;
  const int bn   = sbid % nbn;

  const int wr = wv >> 1;               // wave row 0..1 (64-row slab)
  const int wc = wv & 1;                // wave col 0..1 (64-col slab)

  // staging: thread t loads 16B; row = t/4 (0..63), k-offset = (t%4)*8 bf16
  const int srow = t >> 2;
  const int sk   = (t & 3) * 8;
  const unsigned short* gA = xb + (size_t)(bm * BM + srow) * K_DIM + sk;
  const unsigned short* gB = wb + (size_t)(bn * BN + srow) * K_DIM + sk;
  unsigned short* lA = As + t * 8;      // linear: wave-uniform base + lane*16B
  unsigned short* lB = Bs + t * 8;
  const size_t gstep = (size_t)64 * K_DIM;   // +64 rows for second issue

  f32x4 acc[4][4];
#pragma unroll
  for (int m = 0; m < 4; ++m)
#pragma unroll
    for (int n = 0; n < 4; ++n)
      acc[m][n] = (f32x4){0.f, 0.f, 0.f, 0.f};

  // A-frag: lane l holds A[row = l&15][k = (l>>4)*8 .. +8] ; same for B (K-contiguous rows)
  const int abase = (wr * 64 + lr) * BK + lk * 8;
  const int bbase = (wc * 64 + lr) * BK + lk * 8;

  for (int k0 = 0; k0 < K_DIM; k0 += BK) {
    __syncthreads();                    // prev compute done before overwrite
    gload_lds16(gA,         lA);
    gload_lds16(gA + gstep, lA + 2048);
    gload_lds16(gB,         lB);
    gload_lds16(gB + gstep, lB + 2048);
    gA += BK; gB += BK;
    __syncthreads();                    // drains vmcnt -> LDS tile ready

    bf16x8 af[4], bf_[4];
#pragma unroll
    for (int m = 0; m < 4; ++m)
      af[m] = *reinterpret_cast<const bf16x8*>(&As[abase + m * 16 * BK]);
#pragma unroll
    for (int n = 0; n < 4; ++n)
      bf_[n] = *reinterpret_cast<const bf16x8*>(&Bs[bbase + n * 16 * BK]);
#pragma unroll
    for (int m = 0; m < 4; ++m)
#pragma unroll
      for (int n = 0; n < 4; ++n)
        acc[m][n] = __builtin_amdgcn_mfma_f32_16x16x32_bf16(af[m], bf_[n], acc[m][n], 0, 0, 0);
  }

  // C/D layout (m89-verified): col = lane&15, row = (lane>>4)*4 + reg
  const int orow0 = bm * BM + wr * 64 + lk * 4;
  const int ocol0 = bn * BN + wc * 64 + lr;
#pragma unroll
  for (int m = 0; m < 4; ++m)
#pragma unroll
    for (int n = 0; n < 4; ++n)
#pragma unroll
      for (int j = 0; j < 4; ++j)
        out[(size_t)(orow0 + m * 16 + j) * N_COLS + (ocol0 + n * 16)] = acc[m][n][j];
}

// ---------------- exact fp32 fallback (only if ws too small; correctness insurance) ----------------

__global__ __launch_bounds__(256) void fallback_kernel(const float* __restrict__ x,
                                                       const float* __restrict__ w,
                                                       const float* __restrict__ A,
                                                       const float* __restrict__ Bm,
                                                       float* __restrict__ out) {
  const int o    = blockIdx.x * 256 + threadIdx.x;   // 16 blocks -> 4096 cols
  const int nrow = blockIdx.y;
  float bro[RANK];
#pragma unroll
  for (int r = 0; r < RANK; ++r) bro[r] = Bm[(size_t)o * RANK + r] * 2.0f;
  float bacc = 0.f;
  float tacc[RANK];
#pragma unroll
  for (int r = 0; r < RANK; ++r) tacc[r] = 0.f;
  for (int k = 0; k < K_DIM; ++k) {
    float xv = x[(size_t)nrow * K_DIM + k];
    bacc += xv * w[(size_t)o * K_DIM + k];
#pragma unroll
    for (int r = 0; r < RANK; ++r) tacc[r] += xv * A[(size_t)r * K_DIM + k];
  }
  float res = bacc;
#pragma unroll
  for (int r = 0; r < RANK; ++r) res += bro[r] * tacc[r];
  out[(size_t)nrow * N_COLS + o] = res;
}

// ---------------- launch ----------------

extern "C" void kernel_launch(void* const* d_in, const int* in_sizes, int n_in,
                              void* d_out, int out_size, void* d_ws, size_t ws_size,
                              hipStream_t stream) {
  const float* x  = (const float*)d_in[0];
  const float* w  = (const float*)d_in[1];
  const float* A  = (const float*)d_in[2];
  const float* Bm = (const float*)d_in[3];
  float* out = (float*)d_out;

  const size_t need = ((size_t)N_ROWS * K_DIM + (size_t)N_COLS * K_DIM) * sizeof(unsigned short);
  if (ws_size < need) {
    dim3 grid(N_COLS / 256, N_ROWS);
    fallback_kernel<<<grid, 256, 0, stream>>>(x, w, A, Bm, out);
    return;
  }

  unsigned short* xb = (unsigned short*)d_ws;                       // 64 MiB
  unsigned short* wb = xb + (size_t)N_ROWS * K_DIM;                 // 32 MiB

  conv_x_kernel<<<(N_ROWS * K_DIM / 4) / 256, 256, 0, stream>>>(x, xb);
  make_weff_kernel<<<(N_COLS * K_DIM / 4) / 256, 256, 0, stream>>>(w, A, Bm, wb);

  const int grid_gemm = (N_ROWS / BM) * (N_COLS / BN);              // 64*32 = 2048
  gemm_bf16_kernel<<<grid_gemm, 256, 0, stream>>>(xb, wb, out);
}

// Round 2
// 319.421 us; speedup vs baseline: 1.3445x; 1.3445x over previous
//
#include <hip/hip_runtime.h>

// LoRALinear: out[8192,4096] = x @ W.T + 2.0*(x@A.T)@B.T
// = x @ (W + 2*B@A).T  -> one bf16 MFMA GEMM (8-phase 256x256 template)

#define N_ROWS 8192
#define K_DIM  4096
#define N_COLS 4096
#define RANK   16
#define BK     64
#define NT     (K_DIM / BK)   // 64 K-tiles

typedef __bf16 bf16x8 __attribute__((ext_vector_type(8)));
typedef float  f32x4  __attribute__((ext_vector_type(4)));

__device__ __forceinline__ unsigned short f2bf(float f) {
  unsigned int u = __builtin_bit_cast(unsigned int, f);
  u += 0x7FFFu + ((u >> 16) & 1u);   // RNE
  return (unsigned short)(u >> 16);
}

// ---------------- conversion kernels ----------------

__global__ __launch_bounds__(256) void conv_x_kernel(const float* __restrict__ x,
                                                     unsigned short* __restrict__ xb) {
  size_t idx = (size_t)blockIdx.x * blockDim.x + threadIdx.x;
  const float4 v = *reinterpret_cast<const float4*>(x + idx * 4);
  ushort4 r;
  r.x = f2bf(v.x); r.y = f2bf(v.y); r.z = f2bf(v.z); r.w = f2bf(v.w);
  *reinterpret_cast<ushort4*>(xb + idx * 4) = r;
}

__global__ __launch_bounds__(256) void make_weff_kernel(const float* __restrict__ w,
                                                        const float* __restrict__ A,
                                                        const float* __restrict__ Bm,
                                                        unsigned short* __restrict__ wb) {
  size_t idx = (size_t)blockIdx.x * blockDim.x + threadIdx.x;
  int o  = (int)(idx >> 10);
  int ic = (int)(idx & 1023) << 2;
  const float4 wv = *reinterpret_cast<const float4*>(w + (size_t)o * K_DIM + ic);
  float a0 = wv.x, a1 = wv.y, a2 = wv.z, a3 = wv.w;
  float br[RANK];
#pragma unroll
  for (int r4 = 0; r4 < RANK / 4; ++r4) {
    const float4 bv = *reinterpret_cast<const float4*>(Bm + (size_t)o * RANK + r4 * 4);
    br[r4 * 4 + 0] = bv.x; br[r4 * 4 + 1] = bv.y;
    br[r4 * 4 + 2] = bv.z; br[r4 * 4 + 3] = bv.w;
  }
#pragma unroll
  for (int r = 0; r < RANK; ++r) {
    const float4 av = *reinterpret_cast<const float4*>(A + (size_t)r * K_DIM + ic);
    float b2 = br[r] * 2.0f;
    a0 += b2 * av.x; a1 += b2 * av.y; a2 += b2 * av.z; a3 += b2 * av.w;
  }
  ushort4 rr;
  rr.x = f2bf(a0); rr.y = f2bf(a1); rr.z = f2bf(a2); rr.w = f2bf(a3);
  *reinterpret_cast<ushort4*>(wb + (size_t)o * K_DIM + ic) = rr;
}

// ---------------- 8-phase 256x256 bf16 MFMA GEMM ----------------
// LDS: A[2buf][2half][128][64]b16 @0..64K, B same @64K..128K. half = 16384B.
// Swizzle (within a [128][64] half, 128B rows): phys = logical ^ ((row&7)<<4).
// Staging dest is linear (global_load_lds); global SOURCE is pre-swizzled.
// Wave (wr 0..1, wc 0..3); interleaved frag ownership:
//   C row = mf*32 + wr*16 + (lane>>4)*4 + j   (mf 0..7; mf<4 -> A-half0)
//   C col = nf*64 + wc*16 + (lane&15)         (nf 0..3; nf<2 -> B-half0)
// Per-tile quadrants: ph1(A0,B0) ph2(A0,B1) ph3(A1,B1) ph4(A1,B0)
// Stages: ph1: A1(t+1), ph2: B0(t+1), ph3: A0(t+2), ph4: B1(t+2); vmcnt(4)@ph4.

__device__ __forceinline__ void gload_lds16(const void* g, void* l) {
  __builtin_amdgcn_global_load_lds(
      (__attribute__((address_space(1))) void*)g,
      (__attribute__((address_space(3))) void*)l, 16, 0, 0);
}

__global__ __launch_bounds__(512, 2) void gemm_bf16_8phase(
    const unsigned short* __restrict__ xb, const unsigned short* __restrict__ wb,
    float* __restrict__ out) {
  __shared__ __align__(16) char smem[131072];

  const int t  = threadIdx.x;
  const int l  = t & 63;
  const int wv = t >> 6;
  const int lr = l & 15;
  const int lk = l >> 4;
  const int wr = wv >> 2;     // 0..1
  const int wc = wv & 3;      // 0..3

  // XCD-aware bijective swizzle: 512 blocks % 8 == 0
  const int bid  = blockIdx.x;
  const int sbid = (bid & 7) * 64 + (bid >> 3);
  const int bm   = sbid >> 4;   // 0..31
  const int bn   = sbid & 15;   // 0..15

  // ---- staging (per-thread): linear LDS dest t*16 (+j*8192); swizzled global src
  const int srow = t >> 3;                                  // 0..63
  const int scol = ((t & 7) ^ ((t >> 3) & 7)) << 3;         // elements
  const unsigned short* gA = xb + (size_t)(bm * 256 + srow) * K_DIM + scol;
  const unsigned short* gB = wb + (size_t)(bn * 256 + srow) * K_DIM + scol;
  char* ldsA = smem + t * 16;            // + buf*32768 + half*16384 (+ j*8192)
  char* ldsB = smem + 65536 + t * 16;

#define STAGE_A(hh, tk, bufb) do {                                              \
    const unsigned short* _g = gA + (size_t)((hh) * 128) * K_DIM + (size_t)(tk) * BK; \
    char* _l = ldsA + (bufb) * 32768 + (hh) * 16384;                            \
    gload_lds16(_g, _l);                                                        \
    gload_lds16(_g + (size_t)64 * K_DIM, _l + 8192);                            \
  } while (0)
#define STAGE_B(hh, tk, bufb) do {                                              \
    const unsigned short* _g = gB + (size_t)((hh) * 128) * K_DIM + (size_t)(tk) * BK; \
    char* _l = ldsB + (bufb) * 32768 + (hh) * 16384;                            \
    gload_lds16(_g, _l);                                                        \
    gload_lds16(_g + (size_t)64 * K_DIM, _l + 8192);                            \
  } while (0)

  // ---- ds_read fragment addressing (swizzled granule) ----
  const int g0   = (lk ^ (lr & 7)) << 4;          // kk=0 granule byte
  const int g1   = ((lk + 4) ^ (lr & 7)) << 4;    // kk=1
  const int aoff = (wr * 16 + lr) * 128;          // + (mf&3)*4096 within half
  const int boff = (wc * 16 + lr) * 128;          // + (nf&1)*8192 within half

  bf16x8 aF[8];   // 4 mf x 2 kk
  bf16x8 bF[4];   // 2 nf x 2 kk
  f32x4 acc[8][4];
#pragma unroll
  for (int m = 0; m < 8; ++m)
#pragma unroll
    for (int n = 0; n < 4; ++n)
      acc[m][n] = (f32x4){0.f, 0.f, 0.f, 0.f};

#define READ_A(hh, bufo) do {                                                   \
    const char* _b = smem + (bufo) + (hh) * 16384 + aoff;                       \
    aF[0] = *(const bf16x8*)(_b + 0 * 4096 + g0);                               \
    aF[1] = *(const bf16x8*)(_b + 0 * 4096 + g1);                               \
    aF[2] = *(const bf16x8*)(_b + 1 * 4096 + g0);                               \
    aF[3] = *(const bf16x8*)(_b + 1 * 4096 + g1);                               \
    aF[4] = *(const bf16x8*)(_b + 2 * 4096 + g0);                               \
    aF[5] = *(const bf16x8*)(_b + 2 * 4096 + g1);                               \
    aF[6] = *(const bf16x8*)(_b + 3 * 4096 + g0);                               \
    aF[7] = *(const bf16x8*)(_b + 3 * 4096 + g1);                               \
  } while (0)
#define READ_B(hh, bufo) do {                                                   \
    const char* _b = smem + 65536 + (bufo) + (hh) * 16384 + boff;               \
    bF[0] = *(const bf16x8*)(_b + 0 * 8192 + g0);                               \
    bF[1] = *(const bf16x8*)(_b + 0 * 8192 + g1);                               \
    bF[2] = *(const bf16x8*)(_b + 1 * 8192 + g0);                               \
    bF[3] = *(const bf16x8*)(_b + 1 * 8192 + g1);                               \
  } while (0)

#define MFMA_Q(MB, NB) do {                                                     \
    _Pragma("unroll")                                                           \
    for (int mi = 0; mi < 4; ++mi)                                              \
      _Pragma("unroll")                                                         \
      for (int ni = 0; ni < 2; ++ni)                                            \
        _Pragma("unroll")                                                       \
        for (int kk = 0; kk < 2; ++kk)                                          \
          acc[(MB) + mi][(NB) + ni] = __builtin_amdgcn_mfma_f32_16x16x32_bf16(  \
              aF[mi * 2 + kk], bF[ni * 2 + kk], acc[(MB) + mi][(NB) + ni], 0, 0, 0); \
  } while (0)

#define PH_PRE() do {                                                           \
    __builtin_amdgcn_s_barrier();                                               \
    asm volatile("s_waitcnt lgkmcnt(0)" ::: "memory");                          \
    __builtin_amdgcn_sched_barrier(0);                                          \
    __builtin_amdgcn_s_setprio(1);                                              \
  } while (0)
#define PH_POST() do {                                                          \
    __builtin_amdgcn_s_setprio(0);                                              \
    __builtin_amdgcn_sched_barrier(0);                                          \
    __builtin_amdgcn_s_barrier();                                               \
  } while (0)

  // ---- prologue: tile0 (all 4 halves) + A0(1), B1(1); drain tile0 ----
  STAGE_A(0, 0, 0); STAGE_A(1, 0, 0); STAGE_B(0, 0, 0); STAGE_B(1, 0, 0);
  STAGE_A(0, 1, 1); STAGE_B(1, 1, 1);
  asm volatile("s_waitcnt vmcnt(4)" ::: "memory");
  __builtin_amdgcn_s_barrier();

  for (int tt = 0; tt < NT; ++tt) {
    const int cbuf = tt & 1;
    const int bufo = cbuf * 32768;
    const int nbuf = cbuf ^ 1;

    // phase 1: quadrant (mf0-3, nf0-1)  [reads A0,B0]; stage A1(t+1)
    READ_A(0, bufo); READ_B(0, bufo);
    if (tt + 1 < NT) STAGE_A(1, tt + 1, nbuf);
    PH_PRE(); MFMA_Q(0, 0); PH_POST();

    // phase 2: (mf0-3, nf2-3)  [reads B1]; stage B0(t+1)
    READ_B(1, bufo);
    if (tt + 1 < NT) STAGE_B(0, tt + 1, nbuf);
    PH_PRE(); MFMA_Q(0, 2); PH_POST();

    // phase 3: (mf4-7, nf2-3)  [reads A1]; stage A0(t+2) into current buf
    READ_A(1, bufo);
    if (tt + 2 < NT) STAGE_A(0, tt + 2, cbuf);
    PH_PRE(); MFMA_Q(4, 2); PH_POST();

    // phase 4: (mf4-7, nf0-1)  [re-reads B0]; stage B1(t+2); counted vmcnt
    READ_B(0, bufo);
    if (tt + 2 < NT) STAGE_B(1, tt + 2, cbuf);
    __builtin_amdgcn_s_barrier();
    asm volatile("s_waitcnt lgkmcnt(0)" ::: "memory");
    __builtin_amdgcn_sched_barrier(0);
    __builtin_amdgcn_s_setprio(1);
    MFMA_Q(4, 0);
    __builtin_amdgcn_s_setprio(0);
    __builtin_amdgcn_sched_barrier(0);
    if (tt + 2 < NT) { asm volatile("s_waitcnt vmcnt(4)" ::: "memory"); }
    else             { asm volatile("s_waitcnt vmcnt(0)" ::: "memory"); }
    __builtin_amdgcn_s_barrier();
  }

  // ---- epilogue: C/D layout col=lane&15, row=(lane>>4)*4+j ----
  const int orow = bm * 256 + wr * 16 + lk * 4;
  const int ocol = bn * 256 + wc * 16 + lr;
#pragma unroll
  for (int mf = 0; mf < 8; ++mf)
#pragma unroll
    for (int nf = 0; nf < 4; ++nf)
#pragma unroll
      for (int j = 0; j < 4; ++j)
        out[(size_t)(orow + mf * 32 + j) * N_COLS + (ocol + nf * 64)] = acc[mf][nf][j];

#undef STAGE_A
#undef STAGE_B
#undef READ_A
#undef READ_B
#undef MFMA_Q
#undef PH_PRE
#undef PH_POST
}

// ---------------- exact fp32 fallback (ws too small) ----------------

__global__ __launch_bounds__(256) void fallback_kernel(const float* __restrict__ x,
                                                       const float* __restrict__ w,
                                                       const float* __restrict__ A,
                                                       const float* __restrict__ Bm,
                                                       float* __restrict__ out) {
  const int o    = blockIdx.x * 256 + threadIdx.x;
  const int nrow = blockIdx.y;
  float bro[RANK];
#pragma unroll
  for (int r = 0; r < RANK; ++r) bro[r] = Bm[(size_t)o * RANK + r] * 2.0f;
  float bacc = 0.f;
  float tacc[RANK];
#pragma unroll
  for (int r = 0; r < RANK; ++r) tacc[r] = 0.f;
  for (int k = 0; k < K_DIM; ++k) {
    float xv = x[(size_t)nrow * K_DIM + k];
    bacc += xv * w[(size_t)o * K_DIM + k];
#pragma unroll
    for (int r = 0; r < RANK; ++r) tacc[r] += xv * A[(size_t)r * K_DIM + k];
  }
  float res = bacc;
#pragma unroll
  for (int r = 0; r < RANK; ++r) res += bro[r] * tacc[r];
  out[(size_t)nrow * N_COLS + o] = res;
}

// ---------------- launch ----------------

extern "C" void kernel_launch(void* const* d_in, const int* in_sizes, int n_in,
                              void* d_out, int out_size, void* d_ws, size_t ws_size,
                              hipStream_t stream) {
  const float* x  = (const float*)d_in[0];
  const float* w  = (const float*)d_in[1];
  const float* A  = (const float*)d_in[2];
  const float* Bm = (const float*)d_in[3];
  float* out = (float*)d_out;

  const size_t need = ((size_t)N_ROWS * K_DIM + (size_t)N_COLS * K_DIM) * sizeof(unsigned short);
  if (ws_size < need) {
    dim3 grid(N_COLS / 256, N_ROWS);
    fallback_kernel<<<grid, 256, 0, stream>>>(x, w, A, Bm, out);
    return;
  }

  unsigned short* xb = (unsigned short*)d_ws;
  unsigned short* wb = xb + (size_t)N_ROWS * K_DIM;

  conv_x_kernel<<<(N_ROWS * K_DIM / 4) / 256, 256, 0, stream>>>(x, xb);
  make_weff_kernel<<<(N_COLS * K_DIM / 4) / 256, 256, 0, stream>>>(w, A, Bm, wb);

  const int grid_gemm = (N_ROWS / 256) * (N_COLS / 256);   // 512
  gemm_bf16_8phase<<<grid_gemm, 512, 0, stream>>>(xb, wb, out);
}